// Round 6
// baseline (25.956 us; speedup 1.0000x reference)
//
#include <hip/hip_runtime.h>

// Problem constants (from setup_inputs): B=32, A=5, H=W=52, T=50
#define BB 32
#define AA 5
#define HH 52
#define WW 52
#define TT 50

#define HW (HH * WW)          // 2704
#define AHW (AA * HW)         // 13520
#define N1 (BB * AA * HW)     // 432640
#define N2 (BB * 2 * AA * HW) // 865280

#define BLK 256               // 1 cell per thread -> grid (53, 32), 6784 waves

// ---------------------------------------------------------------------------
// Max-TLP variant: CPT=1. 1696 blocks x 4 waves = 6.6 waves/SIMD (2x R5),
// low VGPR -> up to 8 waves/SIMD resident. Scalar dword accesses, fully
// coalesced (256B/wave). Single barrier; wave 0 builds truth cache + winner
// map (exact JAX argmax semantics) while waves 1..3 issue their global loads.
// Inner 50-iter loop: division-free ignorable test, unroll 10.
// ---------------------------------------------------------------------------
__global__ __launch_bounds__(BLK) void region_target_fused(
    const float* __restrict__ xy, const float* __restrict__ wh,
    const float* __restrict__ obj, const float* __restrict__ truth,
    const float* __restrict__ biases, float* __restrict__ out) {
    __shared__ float  s_truth[TT * 5];
    __shared__ float4 s_tbox[TT];     // (txl, txr, tyt, tyb)
    __shared__ float  s_t06[TT];      // 0.6 * tw * th
    __shared__ int    s_win[BLK];     // winner t per local cell, -1 = none

    const int b = blockIdx.y;
    const int tid = threadIdx.x;
    const int cellbase = blockIdx.x * BLK;
    const int cell = cellbase + tid;
    const bool active = cell < AHW;

    // ---- issue global loads EARLY (before barrier) ----
    int a = 0, j = 0, i = 0, base2 = 0, base2h = 0, base1 = 0;
    float x = 0.f, y = 0.f, w_ = 0.f, h_ = 0.f, o = 0.f;
    float ba0 = 1.0f, ba1 = 1.0f;
    if (active) {
        a = cell / HW;
        int rem = cell - a * HW;
        j = rem / WW;
        i = rem - j * WW;
        base2  = ((b * 2 * AA + a) * HH + j) * WW + i;   // x-half
        base2h = base2 + AA * HW;                         // y-half
        base1  = ((b * AA + a) * HH + j) * WW + i;
        x  = xy[base2];
        y  = xy[base2h];
        w_ = wh[base2];
        h_ = wh[base2h];
        o  = obj[base1];
        ba0 = biases[2 * a];
        ba1 = biases[2 * a + 1];
    }

    // ---- wave-0 prologue, single barrier ----
    s_win[tid] = -1;
    if (tid < TT) {
        const float* tr = truth + (b * TT + tid) * 5;
        float tx = tr[0], ty = tr[1], tw = tr[2], th = tr[3], tc = tr[4];
        s_truth[tid * 5 + 0] = tx;
        s_truth[tid * 5 + 1] = ty;
        s_truth[tid * 5 + 2] = tw;
        s_truth[tid * 5 + 3] = th;
        s_truth[tid * 5 + 4] = tc;
        s_tbox[tid] = make_float4(tx - tw * 0.5f, tx + tw * 0.5f,
                                  ty - th * 0.5f, ty + th * 0.5f);
        s_t06[tid] = 0.6f * (tw * th);

        // argmax over anchors (exact divide, first max wins == jnp.argmax)
        float best = -1.0f;
        int n = 0;
#pragma unroll
        for (int aa = 0; aa < AA; ++aa) {
            float bw0 = biases[2 * aa] / (float)WW;      // uniform -> s_load
            float bh0 = biases[2 * aa + 1] / (float)HH;
            float il2 = fmaxf(-bw0 * 0.5f, -tw * 0.5f);
            float ir2 = fminf(bw0 * 0.5f, tw * 0.5f);
            float it2 = fmaxf(-bh0 * 0.5f, -th * 0.5f);
            float ib2 = fminf(bh0 * 0.5f, th * 0.5f);
            float ov2 = fmaxf(ir2 - il2, 0.0f) * fmaxf(ib2 - it2, 0.0f);
            float iou2 = ov2 / (bw0 * bh0 + tw * th - ov2);
            if (iou2 > best) { best = iou2; n = aa; }
        }
        int ti = (int)(tx * (float)WW);   // trunc == astype(int32) for tx>0
        int tj = (int)(ty * (float)HH);
        bool invalid_pos = (tx <= 0.0f) || (tx >= 1.0f) || (ty <= 0.0f) || (ty >= 1.0f);
        bool valid = !invalid_pos && ti >= 0 && tj >= 0 && ti < WW && tj < HH &&
                     (tw > 0.0f) && (th > 0.0f);
        if (valid) {
            int local = (n * HH + tj) * WW + ti - cellbase;
            if (local >= 0 && local < BLK) atomicMax(&s_win[local], tid);
        }
    }
    __syncthreads();
    if (!active) return;

    // predicted box (mirror reference op order exactly)
    float bx = (x + (float)i) / (float)WW;
    float by = (y + (float)j) / (float)HH;
    float bw = expf(w_) * ba0 / (float)WW;
    float bh = expf(h_) * ba1 / (float)HH;
    float bxl = bx - bw * 0.5f, bxr = bx + bw * 0.5f;
    float byt = by - bh * 0.5f, byb = by + bh * 0.5f;
    float areap = bw * bh;

    // division-free: iou>0.6 <=> 1.6*ov - 0.6*tarea > 0.6*areap (union>0)
    float m = -1e30f;
#pragma unroll 10
    for (int t = 0; t < TT; ++t) {
        float4 tb = s_tbox[t];
        float il = fmaxf(bxl, tb.x);
        float ir = fminf(bxr, tb.y);
        float it = fmaxf(byt, tb.z);
        float ib = fminf(byb, tb.w);
        float ov = fmaxf(ir - il, 0.0f) * fmaxf(ib - it, 0.0f);
        m = fmaxf(m, fmaf(1.6f, ov, -s_t06[t]));
    }
    bool ignorable = m > 0.6f * areap;

    int wsel = s_win[tid];
    bool has = wsel >= 0;

    float vxy0, vxy1, vwh0, vwh1, vwgt, vobj, vnoobj, vlab;
    if (has) {
        int wi = wsel;
        float stx  = s_truth[wi * 5 + 0];
        float sty  = s_truth[wi * 5 + 1];
        float stw  = s_truth[wi * 5 + 2];
        float sth  = s_truth[wi * 5 + 3];
        vxy0 = stx * (float)WW - (float)i;
        vxy1 = sty * (float)HH - (float)j;
        vwh0 = logf(stw * (float)WW / ba0);
        vwh1 = logf(sth * (float)HH / ba1);
        vwgt = 2.0f - stw * sth;
        float il = fmaxf(bxl, stx - stw * 0.5f);
        float ir = fminf(bxr, stx + stw * 0.5f);
        float it = fmaxf(byt, sty - sth * 0.5f);
        float ib = fminf(byb, sty + sth * 0.5f);
        float ov = fmaxf(ir - il, 0.0f) * fmaxf(ib - it, 0.0f);
        vobj = ov / (areap + stw * sth - ov);   // exact rescore divide
        vlab = s_truth[wi * 5 + 4];
        vnoobj = o;
    } else {
        vxy0 = x;  vxy1 = y;
        vwh0 = w_; vwh1 = h_;
        vwgt = 0.0f;
        vobj = o;
        vlab = -1.0f;
        vnoobj = ignorable ? o : 0.0f;
    }

    out[base2]                   = vxy0;
    out[base2h]                  = vxy1;
    out[N2 + base2]              = vwh0;
    out[N2 + base2h]             = vwh1;
    out[2 * N2 + base2]          = vwgt;
    out[2 * N2 + base2h]         = vwgt;
    out[3 * N2 + base1]          = vobj;
    out[3 * N2 + N1 + base1]     = vnoobj;
    out[3 * N2 + 2 * N1 + base1] = vlab;
}

extern "C" void kernel_launch(void* const* d_in, const int* in_sizes, int n_in,
                              void* d_out, int out_size, void* d_ws, size_t ws_size,
                              hipStream_t stream) {
    const float* xy     = (const float*)d_in[0];
    const float* wh     = (const float*)d_in[1];
    const float* obj    = (const float*)d_in[2];
    const float* truth  = (const float*)d_in[3];
    const float* biases = (const float*)d_in[4];
    float* out = (float*)d_out;

    dim3 grid((AHW + BLK - 1) / BLK, BB);   // (53, 32)
    region_target_fused<<<grid, BLK, 0, stream>>>(xy, wh, obj, truth, biases, out);
}

// Round 7
// 19.098 us; speedup vs baseline: 1.3591x; 1.3591x over previous
//
#include <hip/hip_runtime.h>

// Problem constants (from setup_inputs): B=32, A=5, H=W=52, T=50
#define BB 32
#define AA 5
#define HH 52
#define WW 52
#define TT 50

#define HW (HH * WW)          // 2704
#define AHW (AA * HW)         // 13520
#define N1 (BB * AA * HW)     // 432640
#define N2 (BB * 2 * AA * HW) // 865280

#define CPT 2                  // cells per thread (even i0 -> aligned float2)
#define BLK 512
#define CPB (BLK * CPT)        // 1024 cells per block

// ---------------------------------------------------------------------------
// R5 structure with BLK=512: grid (14, 32) = 448 blocks, 3584 waves (same TLP
// as R5) but HALF the prologue replications/barriers. Wave 0 stages truth +
// tbox/t06 + winner map (exact JAX argmax semantics) while waves 1..7 issue
// their global float2 loads early (HBM latency hidden under prologue).
// Inner loop: division-free ignorable test (iou>0.6 <=> 1.6*ov-0.6*ta >
// 0.6*areap), unroll 10. Winner per cell via block-local LDS atomicMax.
// ---------------------------------------------------------------------------
__global__ __launch_bounds__(BLK) void region_target_fused(
    const float* __restrict__ xy, const float* __restrict__ wh,
    const float* __restrict__ obj, const float* __restrict__ truth,
    const float* __restrict__ biases, float* __restrict__ out) {
    __shared__ float  s_truth[TT * 5];
    __shared__ float4 s_tbox[TT];     // (txl, txr, tyt, tyb)
    __shared__ float  s_t06[TT];      // 0.6 * tw * th
    __shared__ int    s_win[CPB];     // winner t per local cell, -1 = none

    const int b = blockIdx.y;
    const int tid = threadIdx.x;
    const int cellbase = blockIdx.x * CPB;
    const int c0 = cellbase + tid * CPT;
    const bool active = c0 < AHW;

    // ---- issue global loads EARLY (before barrier) ----
    int a = 0, j = 0, i0 = 0, base2 = 0, base2h = 0, base1 = 0;
    float2 x2 = {0, 0}, y2 = {0, 0}, w2 = {0, 0}, h2 = {0, 0}, o2 = {0, 0};
    float ba0 = 1.0f, ba1 = 1.0f;
    if (active) {
        a = c0 / HW;
        int rem = c0 - a * HW;
        j = rem / WW;
        i0 = rem - j * WW;                       // even -> float2 aligned
        base2  = ((b * 2 * AA + a) * HH + j) * WW + i0;   // x-half
        base2h = base2 + AA * HW;                          // y-half
        base1  = ((b * AA + a) * HH + j) * WW + i0;
        x2 = *(const float2*)(xy + base2);
        y2 = *(const float2*)(xy + base2h);
        w2 = *(const float2*)(wh + base2);
        h2 = *(const float2*)(wh + base2h);
        o2 = *(const float2*)(obj + base1);
        ba0 = biases[2 * a];
        ba1 = biases[2 * a + 1];
    }

    // ---- wave-0 prologue, single barrier ----
    s_win[tid] = -1;
    s_win[tid + BLK] = -1;
    if (tid < TT) {
        const float* tr = truth + (b * TT + tid) * 5;
        float tx = tr[0], ty = tr[1], tw = tr[2], th = tr[3], tc = tr[4];
        s_truth[tid * 5 + 0] = tx;
        s_truth[tid * 5 + 1] = ty;
        s_truth[tid * 5 + 2] = tw;
        s_truth[tid * 5 + 3] = th;
        s_truth[tid * 5 + 4] = tc;
        s_tbox[tid] = make_float4(tx - tw * 0.5f, tx + tw * 0.5f,
                                  ty - th * 0.5f, ty + th * 0.5f);
        s_t06[tid] = 0.6f * (tw * th);

        // argmax over anchors (exact divide, first max wins == jnp.argmax)
        float best = -1.0f;
        int n = 0;
#pragma unroll
        for (int aa = 0; aa < AA; ++aa) {
            float bw0 = biases[2 * aa] / (float)WW;      // uniform -> s_load
            float bh0 = biases[2 * aa + 1] / (float)HH;
            float il2 = fmaxf(-bw0 * 0.5f, -tw * 0.5f);
            float ir2 = fminf(bw0 * 0.5f, tw * 0.5f);
            float it2 = fmaxf(-bh0 * 0.5f, -th * 0.5f);
            float ib2 = fminf(bh0 * 0.5f, th * 0.5f);
            float ov2 = fmaxf(ir2 - il2, 0.0f) * fmaxf(ib2 - it2, 0.0f);
            float iou2 = ov2 / (bw0 * bh0 + tw * th - ov2);
            if (iou2 > best) { best = iou2; n = aa; }
        }
        int ti = (int)(tx * (float)WW);   // trunc == astype(int32) for tx>0
        int tj = (int)(ty * (float)HH);
        bool invalid_pos = (tx <= 0.0f) || (tx >= 1.0f) || (ty <= 0.0f) || (ty >= 1.0f);
        bool valid = !invalid_pos && ti >= 0 && tj >= 0 && ti < WW && tj < HH &&
                     (tw > 0.0f) && (th > 0.0f);
        if (valid) {
            int local = (n * HH + tj) * WW + ti - cellbase;
            if (local >= 0 && local < CPB) atomicMax(&s_win[local], tid);
        }
    }
    __syncthreads();
    if (!active) return;

    float xs[CPT] = {x2.x, x2.y};
    float ys[CPT] = {y2.x, y2.y};
    float hw_w[CPT] = {w2.x, w2.y};
    float hw_h[CPT] = {h2.x, h2.y};
    float os_[CPT] = {o2.x, o2.y};

    float bxl[CPT], bxr[CPT], byt[CPT], byb[CPT], areap[CPT], m[CPT];
#pragma unroll
    for (int k = 0; k < CPT; ++k) {
        float bx = (xs[k] + (float)(i0 + k)) / (float)WW;   // exact ref order
        float by = (ys[k] + (float)j) / (float)HH;
        float bw = expf(hw_w[k]) * ba0 / (float)WW;
        float bh = expf(hw_h[k]) * ba1 / (float)HH;
        bxl[k] = bx - bw * 0.5f; bxr[k] = bx + bw * 0.5f;
        byt[k] = by - bh * 0.5f; byb[k] = by + bh * 0.5f;
        areap[k] = bw * bh;
        m[k] = -1e30f;
    }

    // division-free: iou>0.6 <=> 1.6*ov - 0.6*tarea > 0.6*areap (union>0)
#pragma unroll 10
    for (int t = 0; t < TT; ++t) {
        float4 tb = s_tbox[t];
        float t06 = s_t06[t];
#pragma unroll
        for (int k = 0; k < CPT; ++k) {
            float il = fmaxf(bxl[k], tb.x);
            float ir = fminf(bxr[k], tb.y);
            float it = fmaxf(byt[k], tb.z);
            float ib = fminf(byb[k], tb.w);
            float ov = fmaxf(ir - il, 0.0f) * fmaxf(ib - it, 0.0f);
            m[k] = fmaxf(m[k], fmaf(1.6f, ov, -t06));
        }
    }

    float vxy0[CPT], vxy1[CPT], vwh0[CPT], vwh1[CPT], vwgt[CPT];
    float vobj[CPT], vnoobj[CPT], vlab[CPT];
#pragma unroll
    for (int k = 0; k < CPT; ++k) {
        bool ignorable = m[k] > 0.6f * areap[k];
        int wsel = s_win[tid * CPT + k];
        bool has = wsel >= 0;
        if (has) {
            int wi = wsel;
            float stx  = s_truth[wi * 5 + 0];
            float sty  = s_truth[wi * 5 + 1];
            float stw  = s_truth[wi * 5 + 2];
            float sth  = s_truth[wi * 5 + 3];
            vxy0[k] = stx * (float)WW - (float)(i0 + k);
            vxy1[k] = sty * (float)HH - (float)j;
            vwh0[k] = logf(stw * (float)WW / ba0);
            vwh1[k] = logf(sth * (float)HH / ba1);
            vwgt[k] = 2.0f - stw * sth;
            float il = fmaxf(bxl[k], stx - stw * 0.5f);
            float ir = fminf(bxr[k], stx + stw * 0.5f);
            float it = fmaxf(byt[k], sty - sth * 0.5f);
            float ib = fminf(byb[k], sty + sth * 0.5f);
            float ov = fmaxf(ir - il, 0.0f) * fmaxf(ib - it, 0.0f);
            vobj[k] = ov / (areap[k] + stw * sth - ov);   // exact rescore divide
            vlab[k] = s_truth[wi * 5 + 4];
            vnoobj[k] = os_[k];
        } else {
            vxy0[k] = xs[k];  vxy1[k] = ys[k];
            vwh0[k] = hw_w[k]; vwh1[k] = hw_h[k];
            vwgt[k] = 0.0f;
            vobj[k] = os_[k];
            vlab[k] = -1.0f;
            vnoobj[k] = ignorable ? os_[k] : 0.0f;
        }
    }

    *(float2*)(out + base2)                   = make_float2(vxy0[0], vxy0[1]);
    *(float2*)(out + base2h)                  = make_float2(vxy1[0], vxy1[1]);
    *(float2*)(out + N2 + base2)              = make_float2(vwh0[0], vwh0[1]);
    *(float2*)(out + N2 + base2h)             = make_float2(vwh1[0], vwh1[1]);
    float2 wgt2 = make_float2(vwgt[0], vwgt[1]);
    *(float2*)(out + 2 * N2 + base2)          = wgt2;
    *(float2*)(out + 2 * N2 + base2h)         = wgt2;
    *(float2*)(out + 3 * N2 + base1)          = make_float2(vobj[0], vobj[1]);
    *(float2*)(out + 3 * N2 + N1 + base1)     = make_float2(vnoobj[0], vnoobj[1]);
    *(float2*)(out + 3 * N2 + 2 * N1 + base1) = make_float2(vlab[0], vlab[1]);
}

extern "C" void kernel_launch(void* const* d_in, const int* in_sizes, int n_in,
                              void* d_out, int out_size, void* d_ws, size_t ws_size,
                              hipStream_t stream) {
    const float* xy     = (const float*)d_in[0];
    const float* wh     = (const float*)d_in[1];
    const float* obj    = (const float*)d_in[2];
    const float* truth  = (const float*)d_in[3];
    const float* biases = (const float*)d_in[4];
    float* out = (float*)d_out;

    dim3 grid((AHW + CPB - 1) / CPB, BB);   // (14, 32) = 448 blocks
    region_target_fused<<<grid, BLK, 0, stream>>>(xy, wh, obj, truth, biases, out);
}